// Round 5
// baseline (107.423 us; speedup 1.0000x reference)
//
#include <hip/hip_runtime.h>
#include <math.h>

// Problem constants (fixed by the reference)
#define G      32
#define NA     1024
#define C      4
#define NMAX   6
#define KHALF  1098      // half of the 2196 nonzero k-vectors (inversion symmetry)
#define KSLICES 18       // ceil(1098/64)
#define WAVES  8
#define BLOCK  (WAVES * 64)
#define APW    (NA / WAVES)   // 128 atoms per wave

typedef float f32x2 __attribute__((ext_vector_type(2)));
typedef float f32x4 __attribute__((ext_vector_type(4)));

// Pack {pos.xyz, 0, q0..q3} per atom into ws: 32 B aligned records.
__global__ __launch_bounds__(256)
void prepack_kernel(const float* __restrict__ q,
                    const float* __restrict__ pos,
                    float* __restrict__ ws)
{
    const int a = blockIdx.x * 256 + threadIdx.x;
    if (a < G * NA) {
        f32x4 p4 = { pos[a * 3 + 0], pos[a * 3 + 1], pos[a * 3 + 2], 0.f };
        const f32x4 qa = *reinterpret_cast<const f32x4*>(q + (size_t)a * 4);
        f32x4* w = reinterpret_cast<f32x4*>(ws + (size_t)a * 8);
        w[0] = p4;
        w[1] = qa;
    }
}

__global__ __launch_bounds__(BLOCK)
void ewald_recip_kernel(const float* __restrict__ ws,
                        const float* __restrict__ cell,
                        float* __restrict__ out)
{
    // per-wave partial S (4 re + 4 im) per k-lane -> 16 KiB (only LDS use)
    __shared__ float s_red[WAVES][64][8];

    const int b    = blockIdx.x;
    const int g    = b / KSLICES;
    const int ks   = b % KSLICES;
    const int t    = threadIdx.x;
    const int wave = t >> 6;
    const int lane = t & 63;

    // ---- per-thread (wave-uniform) cell inverse + det ----
    const float* M = cell + (size_t)g * 9;
    const float m00 = M[0], m01 = M[1], m02 = M[2];
    const float m10 = M[3], m11 = M[4], m12 = M[5];
    const float m20 = M[6], m21 = M[7], m22 = M[8];
    const float c00 =  (m11 * m22 - m12 * m21);
    const float c01 = -(m10 * m22 - m12 * m20);
    const float c02 =  (m10 * m21 - m11 * m20);
    const float c10 = -(m01 * m22 - m02 * m21);
    const float c11 =  (m00 * m22 - m02 * m20);
    const float c12 = -(m00 * m21 - m01 * m20);
    const float c20 =  (m01 * m12 - m02 * m11);
    const float c21 = -(m00 * m12 - m02 * m10);
    const float c22 =  (m00 * m11 - m01 * m10);
    const float det    = m00 * c00 + m01 * c01 + m02 * c02;
    const float invdet = 1.0f / det;

    // ---- decode this lane's half-space k integer triple ----
    const int  kk    = ks * 64 + lane;
    const bool valid = (kk < KHALF);
    int n1, n2, n3;
    if (kk < 1014) {               // n1 in [1,6], n2,n3 full range
        n1 = 1 + kk / 169;
        const int r = kk - (n1 - 1) * 169;
        n2 = r / 13 - 6;
        n3 = r - (r / 13) * 13 - 6;
    } else if (kk < 1092) {        // n1 = 0, n2 in [1,6]
        const int j = kk - 1014;
        n1 = 0;
        n2 = 1 + j / 13;
        n3 = j - (j / 13) * 13 - 6;
    } else {                        // n1 = n2 = 0, n3 in [1,6]
        n1 = 0; n2 = 0;
        n3 = kk - 1091;            // garbage for kk>=1098, masked later
    }
    const float fn1 = (float)n1, fn2 = (float)n2, fn3 = (float)n3;

    // k-vector in REVOLUTION units (no 2*pi): kr[d] = sum_j n_j * inv[d][j]
    const float kr0 = (fn1 * c00 + fn2 * c10 + fn3 * c20) * invdet;
    const float kr1 = (fn1 * c01 + fn2 * c11 + fn3 * c21) * invdet;
    const float kr2 = (fn1 * c02 + fn2 * c12 + fn3 * c22) * invdet;

    // ---- inner loop: wave-uniform broadcast loads from prepacked ws ----
    f32x2 aR01 = {0.f, 0.f}, aR23 = {0.f, 0.f};
    f32x2 aI01 = {0.f, 0.f}, aI23 = {0.f, 0.f};
    {
        const int a0 = wave * APW;
        const f32x4* rec = reinterpret_cast<const f32x4*>(ws) +
                           (size_t)2 * ((size_t)g * NA + a0);
        #pragma unroll 4
        for (int a = 0; a < APW; ++a) {
            const f32x4 pp = rec[2 * a];
            const f32x4 qa = rec[2 * a + 1];
            // phase in revolutions
            const float ph = fmaf(pp.x, kr0, fmaf(pp.y, kr1, pp.z * kr2));
            const float u  = __builtin_amdgcn_fractf(ph);   // [0,1)
            const float sn = __builtin_amdgcn_sinf(u);      // sin(2*pi*u)
            const float cs = __builtin_amdgcn_cosf(u);      // cos(2*pi*u)
            const f32x2 cs2 = {cs, cs};
            const f32x2 sn2 = {sn, sn};
            const f32x2 q01 = {qa.x, qa.y};
            const f32x2 q23 = {qa.z, qa.w};
            aR01 = __builtin_elementwise_fma(q01, cs2, aR01);
            aR23 = __builtin_elementwise_fma(q23, cs2, aR23);
            aI01 = __builtin_elementwise_fma(q01, sn2, aI01);
            aI23 = __builtin_elementwise_fma(q23, sn2, aI23);
        }
    }

    // ---- reduce partial S across waves via LDS ----
    {
        float* rp = s_red[wave][lane];
        rp[0] = aR01.x; rp[1] = aR01.y; rp[2] = aR23.x; rp[3] = aR23.y;
        rp[4] = aI01.x; rp[5] = aI01.y; rp[6] = aI23.x; rp[7] = aI23.y;
    }
    __syncthreads();

    if (t < 64) {
        float r0 = 0.f, r1 = 0.f, r2 = 0.f, r3 = 0.f;
        float i0 = 0.f, i1 = 0.f, i2 = 0.f, i3 = 0.f;
        #pragma unroll
        for (int w = 0; w < WAVES; ++w) {
            const float* p = s_red[w][lane];
            r0 += p[0]; r1 += p[1]; r2 += p[2]; r3 += p[3];
            i0 += p[4]; i1 += p[5]; i2 += p[6]; i3 += p[7];
        }
        const float s2 = r0 * r0 + r1 * r1 + r2 * r2 + r3 * r3
                       + i0 * i0 + i1 * i1 + i2 * i2 + i3 * i3;
        const float kk2 = kr0 * kr0 + kr1 * kr1 + kr2 * kr2;
        const float fourpi2 = 4.0f * (float)M_PI * (float)M_PI;
        const float k2 = fourpi2 * kk2;                      // true |k|^2
        const float wt = 4.0f * (float)M_PI * __expf(-0.5f * k2) / fmaxf(k2, 1e-12f);
        // half-space sum: E = (1/(2V)) * 2 * sum_half = sum_half / V
        float contrib = valid ? wt * s2 : 0.0f;
        #pragma unroll
        for (int off = 32; off > 0; off >>= 1)
            contrib += __shfl_down(contrib, off, 64);
        if (lane == 0)
            atomicAdd(&out[g], contrib * fabsf(invdet));
    }
}

extern "C" void kernel_launch(void* const* d_in, const int* in_sizes, int n_in,
                              void* d_out, int out_size, void* d_ws, size_t ws_size,
                              hipStream_t stream) {
    const float* q    = (const float*)d_in[0];   // [G*NA, C]
    const float* pos  = (const float*)d_in[1];   // [G*NA, 3]
    const float* cell = (const float*)d_in[2];   // [G, 3, 3]
    // d_in[3] = batch (unused: equal-sized sorted segments)
    float* out = (float*)d_out;                  // [G] f32
    float* ws  = (float*)d_ws;                   // prepacked atom records (1 MiB)

    hipMemsetAsync(out, 0, G * sizeof(float), stream);

    prepack_kernel<<<(G * NA + 255) / 256, 256, 0, stream>>>(q, pos, ws);

    dim3 grid(G * KSLICES);
    dim3 block(BLOCK);
    ewald_recip_kernel<<<grid, block, 0, stream>>>(ws, cell, out);
}

// Round 10
// 83.946 us; speedup vs baseline: 1.2797x; 1.2797x over previous
//
#include <hip/hip_runtime.h>
#include <math.h>

// Problem constants (fixed by the reference)
#define G      32
#define NA     1024
#define C      4
#define KHALF  1098      // half of the 2196 nonzero k-vectors (inversion symmetry)
#define KSLICES 18       // ceil(1098/64)
#define WAVES  8
#define BLOCK  (WAVES * 64)
#define APW    (NA / WAVES)   // 128 atoms per wave

typedef float f32x2 __attribute__((ext_vector_type(2)));
typedef float f32x4 __attribute__((ext_vector_type(4)));
typedef float f32x8 __attribute__((ext_vector_type(8)));

// Pack {pos.xyz, 0, q0..q3} per atom into ws: 32 B aligned records.
__global__ __launch_bounds__(256)
void prepack_kernel(const float* __restrict__ q,
                    const float* __restrict__ pos,
                    float* __restrict__ ws)
{
    const int a = blockIdx.x * 256 + threadIdx.x;
    if (a < G * NA) {
        f32x4 p4 = { pos[a * 3 + 0], pos[a * 3 + 1], pos[a * 3 + 2], 0.f };
        const f32x4 qa = *reinterpret_cast<const f32x4*>(q + (size_t)a * 4);
        f32x4* w = reinterpret_cast<f32x4*>(ws + (size_t)a * 8);
        w[0] = p4;
        w[1] = qa;
    }
}

// 4 atom records (32B each) per chunk via scalar loads into SGPRs.
#define LOAD4(R0, R1, R2, R3, P) do {                                      \
    asm volatile("s_load_dwordx8 %0, %1, 0x0"  : "=s"(R0) : "s"(P));        \
    asm volatile("s_load_dwordx8 %0, %1, 0x20" : "=s"(R1) : "s"(P));        \
    asm volatile("s_load_dwordx8 %0, %1, 0x40" : "=s"(R2) : "s"(P));        \
    asm volatile("s_load_dwordx8 %0, %1, 0x60" : "=s"(R3) : "s"(P));        \
} while (0)

// Drain SMEM; "+s" ties the waited values so uses can't be hoisted above.
#define WAIT4(R0, R1, R2, R3)                                              \
    asm volatile("s_waitcnt lgkmcnt(0)"                                     \
                 : "+s"(R0), "+s"(R1), "+s"(R2), "+s"(R3))

__global__ __launch_bounds__(BLOCK)
void ewald_recip_kernel(const float* __restrict__ ws,
                        const float* __restrict__ cell,
                        float* __restrict__ out)
{
    // per-wave partial S (4 re + 4 im) per k-lane -> 16 KiB (only LDS use)
    __shared__ float s_red[WAVES][64][8];

    const int b    = blockIdx.x;
    const int g    = b / KSLICES;
    const int ks   = b % KSLICES;
    const int t    = threadIdx.x;
    const int wave = t >> 6;
    const int lane = t & 63;

    // ---- per-thread (wave-uniform) cell inverse + det ----
    const float* M = cell + (size_t)g * 9;
    const float m00 = M[0], m01 = M[1], m02 = M[2];
    const float m10 = M[3], m11 = M[4], m12 = M[5];
    const float m20 = M[6], m21 = M[7], m22 = M[8];
    const float c00 =  (m11 * m22 - m12 * m21);
    const float c01 = -(m10 * m22 - m12 * m20);
    const float c02 =  (m10 * m21 - m11 * m20);
    const float c10 = -(m01 * m22 - m02 * m21);
    const float c11 =  (m00 * m22 - m02 * m20);
    const float c12 = -(m00 * m21 - m01 * m20);
    const float c20 =  (m01 * m12 - m02 * m11);
    const float c21 = -(m00 * m12 - m02 * m10);
    const float c22 =  (m00 * m11 - m01 * m10);
    const float det    = m00 * c00 + m01 * c01 + m02 * c02;
    const float invdet = 1.0f / det;

    // ---- decode this lane's half-space k integer triple ----
    const int  kk    = ks * 64 + lane;
    const bool valid = (kk < KHALF);
    int n1, n2, n3;
    if (kk < 1014) {               // n1 in [1,6], n2,n3 full range
        n1 = 1 + kk / 169;
        const int r = kk - (n1 - 1) * 169;
        n2 = r / 13 - 6;
        n3 = r - (r / 13) * 13 - 6;
    } else if (kk < 1092) {        // n1 = 0, n2 in [1,6]
        const int j = kk - 1014;
        n1 = 0;
        n2 = 1 + j / 13;
        n3 = j - (j / 13) * 13 - 6;
    } else {                        // n1 = n2 = 0, n3 in [1,6]
        n1 = 0; n2 = 0;
        n3 = kk - 1091;            // garbage for kk>=1098, masked later
    }
    const float fn1 = (float)n1, fn2 = (float)n2, fn3 = (float)n3;

    // k-vector in REVOLUTION units (no 2*pi): kr[d] = sum_j n_j * inv[d][j]
    const float kr0 = (fn1 * c00 + fn2 * c10 + fn3 * c20) * invdet;
    const float kr1 = (fn1 * c01 + fn2 * c11 + fn3 * c21) * invdet;
    const float kr2 = (fn1 * c02 + fn2 * c12 + fn3 * c22) * invdet;

    // ---- inner loop: SGPR double-buffered scalar-load atom streaming ----
    f32x2 aR01 = {0.f, 0.f}, aR23 = {0.f, 0.f};
    f32x2 aI01 = {0.f, 0.f}, aI23 = {0.f, 0.f};

    // wave-uniform byte offset into this graph's records, via readfirstlane
    const unsigned wvByte = (unsigned)__builtin_amdgcn_readfirstlane(wave * APW * 32);
    const char* pa = reinterpret_cast<const char*>(ws)
                   + (size_t)g * NA * 32 + wvByte;

    auto comp = [&](const f32x8& rec) {
        const float ph = fmaf(rec[0], kr0, fmaf(rec[1], kr1, rec[2] * kr2));
        const float u  = __builtin_amdgcn_fractf(ph);   // [0,1) revolutions
        const float sn = __builtin_amdgcn_sinf(u);      // sin(2*pi*u)
        const float cs = __builtin_amdgcn_cosf(u);      // cos(2*pi*u)
        const f32x2 cs2 = {cs, cs};
        const f32x2 sn2 = {sn, sn};
        const f32x2 q01 = {rec[4], rec[5]};
        const f32x2 q23 = {rec[6], rec[7]};
        aR01 = __builtin_elementwise_fma(q01, cs2, aR01);
        aR23 = __builtin_elementwise_fma(q23, cs2, aR23);
        aI01 = __builtin_elementwise_fma(q01, sn2, aI01);
        aI23 = __builtin_elementwise_fma(q23, sn2, aI23);
    };

    {
        f32x8 A0, A1, A2, A3, B0, B1, B2, B3;
        LOAD4(A0, A1, A2, A3, pa);  pa += 128;
        // 15 double iterations (8 atoms each) + epilogue pair = 128 atoms
        #pragma unroll 1
        for (int it = 0; it < 15; ++it) {
            WAIT4(A0, A1, A2, A3);
            LOAD4(B0, B1, B2, B3, pa);  pa += 128;
            comp(A0); comp(A1); comp(A2); comp(A3);
            WAIT4(B0, B1, B2, B3);
            LOAD4(A0, A1, A2, A3, pa);  pa += 128;
            comp(B0); comp(B1); comp(B2); comp(B3);
        }
        WAIT4(A0, A1, A2, A3);
        LOAD4(B0, B1, B2, B3, pa);
        comp(A0); comp(A1); comp(A2); comp(A3);
        WAIT4(B0, B1, B2, B3);
        comp(B0); comp(B1); comp(B2); comp(B3);
    }

    // ---- reduce partial S across waves via LDS ----
    {
        float* rp = s_red[wave][lane];
        rp[0] = aR01.x; rp[1] = aR01.y; rp[2] = aR23.x; rp[3] = aR23.y;
        rp[4] = aI01.x; rp[5] = aI01.y; rp[6] = aI23.x; rp[7] = aI23.y;
    }
    __syncthreads();

    if (t < 64) {
        float r0 = 0.f, r1 = 0.f, r2 = 0.f, r3 = 0.f;
        float i0 = 0.f, i1 = 0.f, i2 = 0.f, i3 = 0.f;
        #pragma unroll
        for (int w = 0; w < WAVES; ++w) {
            const float* p = s_red[w][lane];
            r0 += p[0]; r1 += p[1]; r2 += p[2]; r3 += p[3];
            i0 += p[4]; i1 += p[5]; i2 += p[6]; i3 += p[7];
        }
        const float s2 = r0 * r0 + r1 * r1 + r2 * r2 + r3 * r3
                       + i0 * i0 + i1 * i1 + i2 * i2 + i3 * i3;
        const float kk2 = kr0 * kr0 + kr1 * kr1 + kr2 * kr2;
        const float fourpi2 = 4.0f * (float)M_PI * (float)M_PI;
        const float k2 = fourpi2 * kk2;                      // true |k|^2
        const float wt = 4.0f * (float)M_PI * __expf(-0.5f * k2) / fmaxf(k2, 1e-12f);
        // half-space sum: E = (1/(2V)) * 2 * sum_half = sum_half / V
        float contrib = valid ? wt * s2 : 0.0f;
        #pragma unroll
        for (int off = 32; off > 0; off >>= 1)
            contrib += __shfl_down(contrib, off, 64);
        if (lane == 0)
            atomicAdd(&out[g], contrib * fabsf(invdet));
    }
}

extern "C" void kernel_launch(void* const* d_in, const int* in_sizes, int n_in,
                              void* d_out, int out_size, void* d_ws, size_t ws_size,
                              hipStream_t stream) {
    const float* q    = (const float*)d_in[0];   // [G*NA, C]
    const float* pos  = (const float*)d_in[1];   // [G*NA, 3]
    const float* cell = (const float*)d_in[2];   // [G, 3, 3]
    // d_in[3] = batch (unused: equal-sized sorted segments)
    float* out = (float*)d_out;                  // [G] f32
    float* ws  = (float*)d_ws;                   // prepacked atom records (1 MiB)

    hipMemsetAsync(out, 0, G * sizeof(float), stream);

    prepack_kernel<<<(G * NA + 255) / 256, 256, 0, stream>>>(q, pos, ws);

    dim3 grid(G * KSLICES);
    dim3 block(BLOCK);
    ewald_recip_kernel<<<grid, block, 0, stream>>>(ws, cell, out);
}